// Round 4
// baseline (330.321 us; speedup 1.0000x reference)
//
#include <hip/hip_runtime.h>

// ---------- types ----------
typedef __attribute__((ext_vector_type(8))) __bf16 bf16x8;   // MFMA A/B frag (4 VGPR)
typedef __attribute__((ext_vector_type(4))) float  f32x4;    // MFMA C/D frag
typedef __attribute__((ext_vector_type(4))) unsigned short us4;
typedef __attribute__((ext_vector_type(2))) unsigned int u32x2;

#define QK_SCALE 0.180336880111112f   // 0.125 * log2(e): softmax runs in exp2 domain

__device__ __forceinline__ unsigned short f2bf(float f) {
    unsigned u = __float_as_uint(f);
    u += 0x7fffu + ((u >> 16) & 1u);          // RNE, inputs are finite
    return (unsigned short)(u >> 16);
}

__device__ __forceinline__ unsigned cvt_pk_bf16(float lo, float hi) {
    unsigned r;
    asm("v_cvt_pk_bf16_f32 %0, %1, %2" : "=v"(r) : "v"(lo), "v"(hi));
    return r;
}

__device__ __forceinline__ void gload_lds16(const void* g, void* l) {
    __builtin_amdgcn_global_load_lds((const __attribute__((address_space(1))) void*)g,
                                     (__attribute__((address_space(3))) void*)l, 16, 0, 0);
}

template <int CTRL>
__device__ __forceinline__ float dpp_mov(float x) {
    return __int_as_float(__builtin_amdgcn_update_dpp(0, __float_as_int(x), CTRL, 0xf, 0xf, true));
}
// reductions across the 16-lane row group (row_ror:1/2/4/8) — VALU, no DS pipe
__device__ __forceinline__ float rmax16(float v) {
    v = fmaxf(v, dpp_mov<0x121>(v));
    v = fmaxf(v, dpp_mov<0x122>(v));
    v = fmaxf(v, dpp_mov<0x124>(v));
    v = fmaxf(v, dpp_mov<0x128>(v));
    return v;
}
__device__ __forceinline__ float rsum16(float v) {
    v += dpp_mov<0x121>(v);
    v += dpp_mov<0x122>(v);
    v += dpp_mov<0x124>(v);
    v += dpp_mov<0x128>(v);
    return v;
}

// ---------- fp32 -> bf16 ----------
__global__ __launch_bounds__(256) void f32_to_bf16_k(const float* __restrict__ in,
                                                     unsigned short* __restrict__ out, int n) {
    int i = (blockIdx.x * 256 + threadIdx.x) * 4;
    if (i + 3 < n) {
        float4 v = *(const float4*)(in + i);
        us4 o;
        o.x = f2bf(v.x); o.y = f2bf(v.y); o.z = f2bf(v.z); o.w = f2bf(v.w);
        *(us4*)(out + i) = o;
    }
}

// w1 conversion with QK_SCALE folded into the q-chunk rows [1024,2048)
__global__ __launch_bounds__(256) void cvt_w1_k(const float* __restrict__ in,
                                                unsigned short* __restrict__ out) {
    int i = (blockIdx.x * 256 + threadIdx.x) * 4;
    float4 v = *(const float4*)(in + i);
    const int row = i >> 10;
    const float s = (row >= 1024 && row < 2048) ? QK_SCALE : 1.0f;
    us4 o;
    o.x = f2bf(v.x * s); o.y = f2bf(v.y * s); o.z = f2bf(v.z * s); o.w = f2bf(v.w * s);
    *(us4*)(out + i) = o;
}

// ---------- GEMM: C[M,N] = A[M,K] * B[N,K]^T + bias ----------
template <int OUTF, int QS>
__global__ __launch_bounds__(256, 2) void gemm_bt(const unsigned short* __restrict__ A,
                                                  const unsigned short* __restrict__ B,
                                                  const float* __restrict__ bias,
                                                  void* __restrict__ Cv,
                                                  int M, int N, int K) {
    __shared__ unsigned short As[4 * 128 * 8];
    __shared__ unsigned short Bs[4 * 128 * 8];
    const int t = threadIdx.x;
    const int lane = t & 63;
    const int w = t >> 6;
    const int wr = w >> 1, wc = w & 1;
    const int lhi = lane >> 4, llo = lane & 15;
    const int bm = blockIdx.y, bn = blockIdx.x;

    f32x4 acc[4][4] = {};

    const unsigned short* Ag = A + (size_t)(bm * 128) * K;
    const unsigned short* Bg = B + (size_t)(bn * 128) * K;

    const int r0 = t & 127, kc0 = t >> 7;
    const int r1 = (256 + t) & 127, kc1 = (256 + t) >> 7;
    const int wbase = (t & ~63) * 8;

    const int KT = K >> 5;
    for (int kt = 0; kt < KT; ++kt) {
        const int k0 = kt * 32;
        gload_lds16(Ag + (size_t)r0 * K + k0 + kc0 * 8, As + wbase);
        gload_lds16(Ag + (size_t)r1 * K + k0 + kc1 * 8, As + 2048 + wbase);
        gload_lds16(Bg + (size_t)r0 * K + k0 + kc0 * 8, Bs + wbase);
        gload_lds16(Bg + (size_t)r1 * K + k0 + kc1 * 8, Bs + 2048 + wbase);
        __syncthreads();

        bf16x8 af[4], bfr[4];
#pragma unroll
        for (int mi = 0; mi < 4; ++mi)
            af[mi] = *(const bf16x8*)(As + lhi * 1024 + (wr * 64 + mi * 16 + llo) * 8);
#pragma unroll
        for (int ni = 0; ni < 4; ++ni)
            bfr[ni] = *(const bf16x8*)(Bs + lhi * 1024 + (wc * 64 + ni * 16 + llo) * 8);
#pragma unroll
        for (int mi = 0; mi < 4; ++mi)
#pragma unroll
            for (int ni = 0; ni < 4; ++ni)
                acc[mi][ni] = __builtin_amdgcn_mfma_f32_16x16x32_bf16(af[mi], bfr[ni], acc[mi][ni], 0, 0, 0);
        __syncthreads();
    }

    const int rowb = bm * 128 + wr * 64;
    const int colb = bn * 128 + wc * 64;
#pragma unroll
    for (int mi = 0; mi < 4; ++mi) {
#pragma unroll
        for (int ni = 0; ni < 4; ++ni) {
            const int col = colb + ni * 16 + llo;
            float bv = bias[col];
            if (QS) bv = (col >= 1024 && col < 2048) ? bv * QK_SCALE : bv;
#pragma unroll
            for (int r = 0; r < 4; ++r) {
                const int row = rowb + mi * 16 + lhi * 4 + r;
                const float v = acc[mi][ni][r] + bv;
                if (OUTF == 0) ((unsigned short*)Cv)[(size_t)row * N + col] = f2bf(v);
                else           ((float*)Cv)[(size_t)row * N + col] = v;
            }
        }
    }
}

// ---------- flash attention ----------
// qkv bf16 [8192][3072], chunks (k,q,v): k=0:1024, q=1024:2048 (pre-scaled), v=2048:3072.
// grid (16 q-tiles, 64 b*h); block 256 = 4 waves, each wave 32 q-rows. KV tiles of 64 keys.
// Key-permuted contraction axis for PV: key' = 4*(key&15) + (key>>4).
//   P stored [row16][key'] (stride 88): lane's 4 nf-values contiguous -> cvt_pk + ds_write_b64.
//   V stored [d][key'] (stride 88): staging thread loads key pair (kA, kA+16), packs u32.
__global__ __launch_bounds__(256) void attn_k(const unsigned short* __restrict__ qkv,
                                              unsigned short* __restrict__ score) {
    __shared__ unsigned short Ks[2][4096];      // [buf][kc8][key64][8]  2x8KB
    __shared__ unsigned short Vt[64 * 88];      // [d][key'] stride 88
    __shared__ unsigned short Pl[4][16 * 88];   // per-wave P scratch [row16][key']

    const int t = threadIdx.x;
    const int lane = t & 63;
    const int w = t >> 6;
    const int lhi = lane >> 4, llo = lane & 15;
    const int b = blockIdx.y >> 4, h = blockIdx.y & 15;
    const int q0 = blockIdx.x * 128;

    const unsigned short* kvb = qkv + (size_t)b * 2048 * 3072 + h * 64;

    // Q fragments: rows q0 + w*32 + mf*16 + llo, k = ds*32 + lhi*8 + e
    bf16x8 qf[2][2];
#pragma unroll
    for (int mf = 0; mf < 2; ++mf) {
        const unsigned short* qp = qkv + (size_t)(b * 2048 + q0 + w * 32 + mf * 16 + llo) * 3072
                                   + 1024 + h * 64 + lhi * 8;
        qf[mf][0] = *(const bf16x8*)qp;
        qf[mf][1] = *(const bf16x8*)(qp + 32);
    }

    f32x4 oacc[2][4] = {};
    float m_[2][4], l_[2][4];
#pragma unroll
    for (int mf = 0; mf < 2; ++mf)
#pragma unroll
        for (int r = 0; r < 4; ++r) { m_[mf][r] = -1e30f; l_[mf][r] = 0.f; }

    // V staging: column c of key'-space pairs; keys kA = 32*(c&1) + (c>>1) and kA+16
    const int c = t & 31, vdc = t >> 5;
    const int kA = ((c & 1) << 5) + (c >> 1);
    const unsigned short* vsrc = kvb + 2048 + (size_t)kA * 3072 + vdc * 8;
    bf16x8 vr0, vr1;

    auto issueK = [&](int kt, int buf) {
        const unsigned short* g = kvb + (size_t)(kt * 64 + lane) * 3072 + w * 8;
        gload_lds16(g,      &Ks[buf][(t & ~63) * 8]);          // kc = w
        gload_lds16(g + 32, &Ks[buf][2048 + (t & ~63) * 8]);   // kc = w+4
    };
    auto issueV = [&](int kt) {
        const unsigned short* g = vsrc + (size_t)kt * 64 * 3072;
        vr0 = *(const bf16x8*)g;
        vr1 = *(const bf16x8*)(g + 16 * 3072);
    };
    auto writeVt = [&]() {
        union { bf16x8 v; unsigned short u[8]; } a_, c_;
        a_.v = vr0; c_.v = vr1;
        unsigned int* V32 = (unsigned int*)Vt;
#pragma unroll
        for (int j = 0; j < 8; ++j)
            V32[(vdc * 8 + j) * 44 + c] = (unsigned int)a_.u[j] | ((unsigned int)c_.u[j] << 16);
    };

    issueK(0, 0);
    __builtin_amdgcn_sched_barrier(0);   // pin: K issue before V issue (in-order vmcnt trick)
    issueV(0);

    for (int kt = 0; kt < 32; ++kt) {
        const int cur = kt & 1;
        if (kt < 31) issueK(kt + 1, cur ^ 1);
        __builtin_amdgcn_sched_barrier(0);           // pin K(t+1) before the vr(t) use below
        writeVt();                                   // compiler's vmcnt wait on vr(t) => K(t) DMA landed
        if (kt < 31) issueV(kt + 1);
        asm volatile("s_waitcnt lgkmcnt(0)" ::: "memory");   // Vt writes visible
        __builtin_amdgcn_sched_barrier(0);
        __builtin_amdgcn_s_barrier();                // NO vmcnt drain: K(t+1)/V(t+1) stay in flight
        __builtin_amdgcn_sched_barrier(0);

        // ---- S = Q K^T (32 x 64 per wave) ----
        f32x4 sa[2][4] = {};
#pragma unroll
        for (int ds = 0; ds < 2; ++ds) {
#pragma unroll
            for (int nf = 0; nf < 4; ++nf) {
                bf16x8 kb = *(const bf16x8*)(&Ks[cur][(ds * 4 + lhi) * 512 + (nf * 16 + llo) * 8]);
                sa[0][nf] = __builtin_amdgcn_mfma_f32_16x16x32_bf16(qf[0][ds], kb, sa[0][nf], 0, 0, 0);
                sa[1][nf] = __builtin_amdgcn_mfma_f32_16x16x32_bf16(qf[1][ds], kb, sa[1][nf], 0, 0, 0);
            }
        }

        // ---- online softmax (exp2 domain), defer-max THR=8 ----
        float pm[2][4];
        bool grow = false;
#pragma unroll
        for (int mf = 0; mf < 2; ++mf)
#pragma unroll
            for (int r = 0; r < 4; ++r) {
                float q = fmaxf(fmaxf(sa[mf][0][r], sa[mf][1][r]), fmaxf(sa[mf][2][r], sa[mf][3][r]));
                q = rmax16(q);
                pm[mf][r] = q;
                grow = grow || (q > m_[mf][r] + 8.f);
            }
        if (__any(grow)) {
#pragma unroll
            for (int mf = 0; mf < 2; ++mf)
#pragma unroll
                for (int r = 0; r < 4; ++r) {
                    const float mn = fmaxf(m_[mf][r], pm[mf][r]);
                    const float cc = __builtin_amdgcn_exp2f(m_[mf][r] - mn);
                    m_[mf][r] = mn;
                    const float p0 = __builtin_amdgcn_exp2f(sa[mf][0][r] - mn);
                    const float p1 = __builtin_amdgcn_exp2f(sa[mf][1][r] - mn);
                    const float p2 = __builtin_amdgcn_exp2f(sa[mf][2][r] - mn);
                    const float p3 = __builtin_amdgcn_exp2f(sa[mf][3][r] - mn);
                    sa[mf][0][r] = p0; sa[mf][1][r] = p1; sa[mf][2][r] = p2; sa[mf][3][r] = p3;
                    l_[mf][r] = l_[mf][r] * cc + (p0 + p1 + p2 + p3);
#pragma unroll
                    for (int nf = 0; nf < 4; ++nf) oacc[mf][nf][r] *= cc;
                }
        } else {
#pragma unroll
            for (int mf = 0; mf < 2; ++mf)
#pragma unroll
                for (int r = 0; r < 4; ++r) {
                    const float p0 = __builtin_amdgcn_exp2f(sa[mf][0][r] - m_[mf][r]);
                    const float p1 = __builtin_amdgcn_exp2f(sa[mf][1][r] - m_[mf][r]);
                    const float p2 = __builtin_amdgcn_exp2f(sa[mf][2][r] - m_[mf][r]);
                    const float p3 = __builtin_amdgcn_exp2f(sa[mf][3][r] - m_[mf][r]);
                    sa[mf][0][r] = p0; sa[mf][1][r] = p1; sa[mf][2][r] = p2; sa[mf][3][r] = p3;
                    l_[mf][r] += (p0 + p1 + p2 + p3);
                }
        }

        // ---- P pack (key'-contiguous) + b64 writes + b128 read-back as A-frags ----
        bf16x8 pa[2][2];
        unsigned short* pw = Pl[w];
#pragma unroll
        for (int mf = 0; mf < 2; ++mf) {
#pragma unroll
            for (int r = 0; r < 4; ++r) {
                u32x2 val;
                val.x = cvt_pk_bf16(sa[mf][0][r], sa[mf][1][r]);   // keys' 4llo+0, +1
                val.y = cvt_pk_bf16(sa[mf][2][r], sa[mf][3][r]);   // keys' 4llo+2, +3
                *(u32x2*)&pw[(lhi * 4 + r) * 88 + llo * 4] = val;
            }
            // in-wave DS ordering: reads below see this mf's writes
            pa[mf][0] = *(const bf16x8*)(pw + llo * 88 + lhi * 8);
            pa[mf][1] = *(const bf16x8*)(pw + llo * 88 + 32 + lhi * 8);
        }

        // ---- O += P V (key'-permuted axis on both sides) ----
#pragma unroll
        for (int ks = 0; ks < 2; ++ks) {
#pragma unroll
            for (int nf = 0; nf < 4; ++nf) {
                bf16x8 vb = *(const bf16x8*)(Vt + (nf * 16 + llo) * 88 + ks * 32 + lhi * 8);
                oacc[0][nf] = __builtin_amdgcn_mfma_f32_16x16x32_bf16(pa[0][ks], vb, oacc[0][nf], 0, 0, 0);
                oacc[1][nf] = __builtin_amdgcn_mfma_f32_16x16x32_bf16(pa[1][ks], vb, oacc[1][nf], 0, 0, 0);
            }
        }
        __builtin_amdgcn_sched_barrier(0);
        __builtin_amdgcn_s_barrier();                // readers done before next tile's writes
        __builtin_amdgcn_sched_barrier(0);
    }

    // ---- epilogue: reduce l across the 16-lane group once, normalize, store ----
#pragma unroll
    for (int mf = 0; mf < 2; ++mf) {
#pragma unroll
        for (int r = 0; r < 4; ++r) {
            const float L = rsum16(l_[mf][r]);
            const float rl = 1.0f / L;
            const int row = b * 2048 + q0 + w * 32 + mf * 16 + lhi * 4 + r;
#pragma unroll
            for (int nf = 0; nf < 4; ++nf)
                score[(size_t)row * 1024 + h * 64 + nf * 16 + llo] = f2bf(oacc[mf][nf][r] * rl);
        }
    }
}

// ---------- launch ----------
extern "C" void kernel_launch(void* const* d_in, const int* in_sizes, int n_in,
                              void* d_out, int out_size, void* d_ws, size_t ws_size,
                              hipStream_t stream) {
    const float* x  = (const float*)d_in[0];
    const float* w1 = (const float*)d_in[1];
    const float* b1 = (const float*)d_in[2];
    const float* w2 = (const float*)d_in[3];
    const float* b2 = (const float*)d_in[4];
    float* out = (float*)d_out;

    char* ws = (char*)d_ws;
    unsigned short* qkv   = (unsigned short*)ws;
    unsigned short* xbf   = (unsigned short*)(ws + 50331648);
    unsigned short* w1bf  = (unsigned short*)(ws + 50331648 + 16777216);
    unsigned short* w2bf  = (unsigned short*)(ws + 50331648 + 16777216 + 6291456);
    unsigned short* score = xbf;  // x dead after GEMM1; alias (stream-ordered)

    f32_to_bf16_k<<<dim3(8388608 / 1024), dim3(256), 0, stream>>>(x,  xbf,  8388608);
    cvt_w1_k<<<dim3(3145728 / 1024), dim3(256), 0, stream>>>(w1, w1bf);
    f32_to_bf16_k<<<dim3(1048576 / 1024), dim3(256), 0, stream>>>(w2, w2bf, 1048576);

    gemm_bt<0, 1><<<dim3(24, 64), dim3(256), 0, stream>>>(xbf, w1bf, b1, (void*)qkv, 8192, 3072, 1024);
    attn_k<<<dim3(16, 64), dim3(256), 0, stream>>>(qkv, score);
    gemm_bt<1, 0><<<dim3(8, 64), dim3(256), 0, stream>>>(score, w2bf, b2, (void*)out, 8192, 1024, 1024);
}

// Round 5
// 283.522 us; speedup vs baseline: 1.1651x; 1.1651x over previous
//
#include <hip/hip_runtime.h>

// ---------- types ----------
typedef __attribute__((ext_vector_type(8))) __bf16 bf16x8;   // MFMA A/B frag (4 VGPR)
typedef __attribute__((ext_vector_type(4))) float  f32x4;    // MFMA C/D frag
typedef __attribute__((ext_vector_type(4))) unsigned short us4;

#define QK_SCALE 0.180336880111112f   // 0.125 * log2(e): softmax runs in exp2 domain

__device__ __forceinline__ unsigned short f2bf(float f) {
    unsigned u = __float_as_uint(f);
    u += 0x7fffu + ((u >> 16) & 1u);          // RNE, inputs are finite
    return (unsigned short)(u >> 16);
}

__device__ __forceinline__ unsigned cvt_pk_bf16(float lo, float hi) {
    unsigned r;
    asm("v_cvt_pk_bf16_f32 %0, %1, %2" : "=v"(r) : "v"(lo), "v"(hi));
    return r;
}

__device__ __forceinline__ void gload_lds16(const void* g, void* l) {
    __builtin_amdgcn_global_load_lds((const __attribute__((address_space(1))) void*)g,
                                     (__attribute__((address_space(3))) void*)l, 16, 0, 0);
}

// ---------- fp32 -> bf16 ----------
__global__ __launch_bounds__(256) void f32_to_bf16_k(const float* __restrict__ in,
                                                     unsigned short* __restrict__ out, int n) {
    int i = (blockIdx.x * 256 + threadIdx.x) * 4;
    if (i + 3 < n) {
        float4 v = *(const float4*)(in + i);
        us4 o;
        o.x = f2bf(v.x); o.y = f2bf(v.y); o.z = f2bf(v.z); o.w = f2bf(v.w);
        *(us4*)(out + i) = o;
    }
}

// w1 conversion with QK_SCALE folded into the q-chunk rows [1024,2048)
__global__ __launch_bounds__(256) void cvt_w1_k(const float* __restrict__ in,
                                                unsigned short* __restrict__ out) {
    int i = (blockIdx.x * 256 + threadIdx.x) * 4;
    float4 v = *(const float4*)(in + i);
    const int row = i >> 10;
    const float s = (row >= 1024 && row < 2048) ? QK_SCALE : 1.0f;
    us4 o;
    o.x = f2bf(v.x * s); o.y = f2bf(v.y * s); o.z = f2bf(v.z * s); o.w = f2bf(v.w * s);
    *(us4*)(out + i) = o;
}

// ---------- GEMM: C[M,N] = A[M,K] * B[N,K]^T + bias ----------
template <int OUTF, int QS>
__global__ __launch_bounds__(256, 2) void gemm_bt(const unsigned short* __restrict__ A,
                                                  const unsigned short* __restrict__ B,
                                                  const float* __restrict__ bias,
                                                  void* __restrict__ Cv,
                                                  int M, int N, int K) {
    __shared__ unsigned short As[4 * 128 * 8];
    __shared__ unsigned short Bs[4 * 128 * 8];
    const int t = threadIdx.x;
    const int lane = t & 63;
    const int w = t >> 6;
    const int wr = w >> 1, wc = w & 1;
    const int lhi = lane >> 4, llo = lane & 15;
    const int bm = blockIdx.y, bn = blockIdx.x;

    f32x4 acc[4][4] = {};

    const unsigned short* Ag = A + (size_t)(bm * 128) * K;
    const unsigned short* Bg = B + (size_t)(bn * 128) * K;

    const int r0 = t & 127, kc0 = t >> 7;
    const int r1 = (256 + t) & 127, kc1 = (256 + t) >> 7;
    const int wbase = (t & ~63) * 8;

    const int KT = K >> 5;
    for (int kt = 0; kt < KT; ++kt) {
        const int k0 = kt * 32;
        gload_lds16(Ag + (size_t)r0 * K + k0 + kc0 * 8, As + wbase);
        gload_lds16(Ag + (size_t)r1 * K + k0 + kc1 * 8, As + 2048 + wbase);
        gload_lds16(Bg + (size_t)r0 * K + k0 + kc0 * 8, Bs + wbase);
        gload_lds16(Bg + (size_t)r1 * K + k0 + kc1 * 8, Bs + 2048 + wbase);
        __syncthreads();

        bf16x8 af[4], bfr[4];
#pragma unroll
        for (int mi = 0; mi < 4; ++mi)
            af[mi] = *(const bf16x8*)(As + lhi * 1024 + (wr * 64 + mi * 16 + llo) * 8);
#pragma unroll
        for (int ni = 0; ni < 4; ++ni)
            bfr[ni] = *(const bf16x8*)(Bs + lhi * 1024 + (wc * 64 + ni * 16 + llo) * 8);
#pragma unroll
        for (int mi = 0; mi < 4; ++mi)
#pragma unroll
            for (int ni = 0; ni < 4; ++ni)
                acc[mi][ni] = __builtin_amdgcn_mfma_f32_16x16x32_bf16(af[mi], bfr[ni], acc[mi][ni], 0, 0, 0);
        __syncthreads();
    }

    const int rowb = bm * 128 + wr * 64;
    const int colb = bn * 128 + wc * 64;
#pragma unroll
    for (int mi = 0; mi < 4; ++mi) {
#pragma unroll
        for (int ni = 0; ni < 4; ++ni) {
            const int col = colb + ni * 16 + llo;
            float bv = bias[col];
            if (QS) bv = (col >= 1024 && col < 2048) ? bv * QK_SCALE : bv;
#pragma unroll
            for (int r = 0; r < 4; ++r) {
                const int row = rowb + mi * 16 + lhi * 4 + r;
                const float v = acc[mi][ni][r] + bv;
                if (OUTF == 0) ((unsigned short*)Cv)[(size_t)row * N + col] = f2bf(v);
                else           ((float*)Cv)[(size_t)row * N + col] = v;
            }
        }
    }
}

// ---------- flash attention (swapped-QK^T, P in-register) ----------
// qkv bf16 [8192][3072], chunks (k,q,v): k=0:1024, q=1024:2048 (pre-scaled), v=2048:3072.
// grid (16 q-tiles, 64 b*h); block 256 = 4 waves x 32 q-rows. KV tiles of 64 keys.
// S^T = mfma(A=K, B=Q): lane holds q-row=llo, keys {16*nfk + 4*lhi + r}.
// PV contraction slot s = ks*32 + lhi*8 + e <-> orig key 16*(2ks+(e>>2)) + 4*lhi + (e&3);
// V staged [d][slot] (stride 88, dbuf): thread c handles slots 2c,2c+1 = consecutive keys kA,kA+1.
// One barrier/tile; K dbuf DMA crosses barrier with vmcnt(2); V regs prefetched one tile ahead.
__global__ __launch_bounds__(256) void attn_k(const unsigned short* __restrict__ qkv,
                                              unsigned short* __restrict__ score) {
    __shared__ unsigned short Ks[2][4096];      // [buf][kc8][key64][8]   2x8KB
    __shared__ unsigned short Vt[2][5632];      // [buf][d64][slot] stride 88  2x11KB

    const int t = threadIdx.x;
    const int lane = t & 63;
    const int w = t >> 6;
    const int lhi = lane >> 4, llo = lane & 15;
    const int b = blockIdx.y >> 4, h = blockIdx.y & 15;
    const int q0 = blockIdx.x * 128;

    const unsigned short* kvb = qkv + (size_t)b * 2048 * 3072 + h * 64;

    // Q fragments (B-operand): rows q0 + w*32 + mf*16 + llo, k = ds*32 + lhi*8 + e
    bf16x8 qf[2][2];
#pragma unroll
    for (int mf = 0; mf < 2; ++mf) {
        const unsigned short* qp = qkv + (size_t)(b * 2048 + q0 + w * 32 + mf * 16 + llo) * 3072
                                   + 1024 + h * 64 + lhi * 8;
        qf[mf][0] = *(const bf16x8*)qp;
        qf[mf][1] = *(const bf16x8*)(qp + 32);
    }

    f32x4 oacc[2][4] = {};
    float m_[2] = {-1e30f, -1e30f}, l_[2] = {0.f, 0.f};

    // V staging: thread (c, vdc) loads keys kA, kA+1 (consecutive) -> u32 col c of d-rows vdc*8..+7
    const int c = t & 31, vdc = t >> 5;
    const int kA = 4 * ((c >> 2) & 3) + 2 * (c & 1) + 16 * (2 * (c >> 4) + ((c >> 1) & 1));
    const unsigned short* vp = kvb + 2048 + (size_t)kA * 3072 + vdc * 8;
    const unsigned short* kp = kvb + (size_t)lane * 3072 + w * 8;
    bf16x8 vr0, vr1;

    // prologue: K(0) DMA, V(0) regs
    gload_lds16(kp,      &Ks[0][(t & ~63) * 8]);
    gload_lds16(kp + 32, &Ks[0][2048 + (t & ~63) * 8]);
    kp += 196608;
    vr0 = *(const bf16x8*)vp;
    vr1 = *(const bf16x8*)(vp + 3072);
    vp += 196608;

    for (int kt = 0; kt < 32; ++kt) {
        const int cur = kt & 1;
        // ---- write V(t) to LDS (auto-wait vr; K(t) DMA stays in flight) ----
        {
            union { bf16x8 v; unsigned short u[8]; } A_, B_;
            A_.v = vr0; B_.v = vr1;
            unsigned* V32 = (unsigned*)&Vt[cur][0];
#pragma unroll
            for (int j = 0; j < 8; ++j)
                V32[(vdc * 8 + j) * 44 + c] = (unsigned)A_.u[j] | ((unsigned)B_.u[j] << 16);
        }
        __builtin_amdgcn_sched_barrier(0);
        if (kt < 31) {                          // prefetch V(t+1) into regs
            vr0 = *(const bf16x8*)vp;
            vr1 = *(const bf16x8*)(vp + 3072);
            vp += 196608;
        }
        __builtin_amdgcn_sched_barrier(0);
        if (kt < 31) asm volatile("s_waitcnt vmcnt(2) lgkmcnt(0)" ::: "memory");  // K(t) landed, V(t+1) flies
        else         asm volatile("s_waitcnt vmcnt(0) lgkmcnt(0)" ::: "memory");
        __builtin_amdgcn_s_barrier();           // ONE barrier per tile
        __builtin_amdgcn_sched_barrier(0);
        if (kt < 31) {                          // K(t+1) DMA (post-barrier: safe vs slow waves' QK(t))
            gload_lds16(kp,      &Ks[cur ^ 1][(t & ~63) * 8]);
            gload_lds16(kp + 32, &Ks[cur ^ 1][2048 + (t & ~63) * 8]);
            kp += 196608;
        }

        // ---- S^T = K Q^T: lane = q-row llo, keys 16*nfk + 4*lhi + r ----
        f32x4 sa[2][4] = {};
#pragma unroll
        for (int ds = 0; ds < 2; ++ds) {
#pragma unroll
            for (int nfk = 0; nfk < 4; ++nfk) {
                bf16x8 kb = *(const bf16x8*)(&Ks[cur][(ds * 4 + lhi) * 512 + (nfk * 16 + llo) * 8]);
                sa[0][nfk] = __builtin_amdgcn_mfma_f32_16x16x32_bf16(kb, qf[0][ds], sa[0][nfk], 0, 0, 0);
                sa[1][nfk] = __builtin_amdgcn_mfma_f32_16x16x32_bf16(kb, qf[1][ds], sa[1][nfk], 0, 0, 0);
            }
        }

        // ---- per-lane online softmax (exp2 domain), defer-max THR=8 ----
        float pmv[2];
#pragma unroll
        for (int mf = 0; mf < 2; ++mf) {
            float p0 = fmaxf(fmaxf(sa[mf][0][0], sa[mf][0][1]), fmaxf(sa[mf][0][2], sa[mf][0][3]));
            float p1 = fmaxf(fmaxf(sa[mf][1][0], sa[mf][1][1]), fmaxf(sa[mf][1][2], sa[mf][1][3]));
            float p2 = fmaxf(fmaxf(sa[mf][2][0], sa[mf][2][1]), fmaxf(sa[mf][2][2], sa[mf][2][3]));
            float p3 = fmaxf(fmaxf(sa[mf][3][0], sa[mf][3][1]), fmaxf(sa[mf][3][2], sa[mf][3][3]));
            float pm = fmaxf(fmaxf(p0, p1), fmaxf(p2, p3));
            pm = fmaxf(pm, __shfl_xor(pm, 16, 64));
            pm = fmaxf(pm, __shfl_xor(pm, 32, 64));
            pmv[mf] = pm;
        }
        const bool grow = (pmv[0] > m_[0] + 8.f) || (pmv[1] > m_[1] + 8.f);
        if (__any(grow)) {
#pragma unroll
            for (int mf = 0; mf < 2; ++mf) {
                const float mn = fmaxf(m_[mf], pmv[mf]);
                const float cc = __builtin_amdgcn_exp2f(m_[mf] - mn);
                m_[mf] = mn;
                l_[mf] *= cc;
                // broadcast cc (indexed by q-row=llo) to O-layout rows lhi*4+r
                const float c0 = __shfl(cc, lhi * 4 + 0, 64);
                const float c1 = __shfl(cc, lhi * 4 + 1, 64);
                const float c2 = __shfl(cc, lhi * 4 + 2, 64);
                const float c3 = __shfl(cc, lhi * 4 + 3, 64);
#pragma unroll
                for (int nf = 0; nf < 4; ++nf) {
                    oacc[mf][nf][0] *= c0; oacc[mf][nf][1] *= c1;
                    oacc[mf][nf][2] *= c2; oacc[mf][nf][3] *= c3;
                }
            }
        }

        // ---- P = exp2(S - m), pack in-register into PV A-frags ----
        bf16x8 pa[2][2];
#pragma unroll
        for (int mf = 0; mf < 2; ++mf) {
            float p[4][4], s = 0.f;
#pragma unroll
            for (int nf = 0; nf < 4; ++nf)
#pragma unroll
                for (int r = 0; r < 4; ++r) {
                    p[nf][r] = __builtin_amdgcn_exp2f(sa[mf][nf][r] - m_[mf]);
                    s += p[nf][r];
                }
            l_[mf] += s;
            union { unsigned u[4]; bf16x8 v; } k0, k1;
            k0.u[0] = cvt_pk_bf16(p[0][0], p[0][1]); k0.u[1] = cvt_pk_bf16(p[0][2], p[0][3]);
            k0.u[2] = cvt_pk_bf16(p[1][0], p[1][1]); k0.u[3] = cvt_pk_bf16(p[1][2], p[1][3]);
            k1.u[0] = cvt_pk_bf16(p[2][0], p[2][1]); k1.u[1] = cvt_pk_bf16(p[2][2], p[2][3]);
            k1.u[2] = cvt_pk_bf16(p[3][0], p[3][1]); k1.u[3] = cvt_pk_bf16(p[3][2], p[3][3]);
            pa[mf][0] = k0.v; pa[mf][1] = k1.v;
        }

        // ---- O += P V (slot-permuted contraction; V B-operand from Vt[cur]) ----
#pragma unroll
        for (int ks = 0; ks < 2; ++ks)
#pragma unroll
            for (int nf = 0; nf < 4; ++nf) {
                bf16x8 vb = *(const bf16x8*)(&Vt[cur][(nf * 16 + llo) * 88 + ks * 32 + lhi * 8]);
                oacc[0][nf] = __builtin_amdgcn_mfma_f32_16x16x32_bf16(pa[0][ks], vb, oacc[0][nf], 0, 0, 0);
                oacc[1][nf] = __builtin_amdgcn_mfma_f32_16x16x32_bf16(pa[1][ks], vb, oacc[1][nf], 0, 0, 0);
            }
        // no bottom barrier: V dbuf + post-barrier K-DMA make it safe
    }

    // ---- epilogue: reduce l over the 4-lane group, broadcast to O rows, store ----
#pragma unroll
    for (int mf = 0; mf < 2; ++mf) {
        float l = l_[mf];
        l += __shfl_xor(l, 16, 64);
        l += __shfl_xor(l, 32, 64);
        const float rl = 1.0f / l;
        const float r0 = __shfl(rl, lhi * 4 + 0, 64);
        const float r1 = __shfl(rl, lhi * 4 + 1, 64);
        const float r2 = __shfl(rl, lhi * 4 + 2, 64);
        const float r3 = __shfl(rl, lhi * 4 + 3, 64);
        const int rowb = b * 2048 + q0 + w * 32 + mf * 16;
#pragma unroll
        for (int nf = 0; nf < 4; ++nf) {
            const int col = h * 64 + nf * 16 + llo;
            score[(size_t)(rowb + lhi * 4 + 0) * 1024 + col] = f2bf(oacc[mf][nf][0] * r0);
            score[(size_t)(rowb + lhi * 4 + 1) * 1024 + col] = f2bf(oacc[mf][nf][1] * r1);
            score[(size_t)(rowb + lhi * 4 + 2) * 1024 + col] = f2bf(oacc[mf][nf][2] * r2);
            score[(size_t)(rowb + lhi * 4 + 3) * 1024 + col] = f2bf(oacc[mf][nf][3] * r3);
        }
    }
}

// ---------- launch ----------
extern "C" void kernel_launch(void* const* d_in, const int* in_sizes, int n_in,
                              void* d_out, int out_size, void* d_ws, size_t ws_size,
                              hipStream_t stream) {
    const float* x  = (const float*)d_in[0];
    const float* w1 = (const float*)d_in[1];
    const float* b1 = (const float*)d_in[2];
    const float* w2 = (const float*)d_in[3];
    const float* b2 = (const float*)d_in[4];
    float* out = (float*)d_out;

    char* ws = (char*)d_ws;
    unsigned short* qkv   = (unsigned short*)ws;
    unsigned short* xbf   = (unsigned short*)(ws + 50331648);
    unsigned short* w1bf  = (unsigned short*)(ws + 50331648 + 16777216);
    unsigned short* w2bf  = (unsigned short*)(ws + 50331648 + 16777216 + 6291456);
    unsigned short* score = xbf;  // x dead after GEMM1; alias (stream-ordered)

    f32_to_bf16_k<<<dim3(8388608 / 1024), dim3(256), 0, stream>>>(x,  xbf,  8388608);
    cvt_w1_k<<<dim3(3145728 / 1024), dim3(256), 0, stream>>>(w1, w1bf);
    f32_to_bf16_k<<<dim3(1048576 / 1024), dim3(256), 0, stream>>>(w2, w2bf, 1048576);

    gemm_bt<0, 1><<<dim3(24, 64), dim3(256), 0, stream>>>(xbf, w1bf, b1, (void*)qkv, 8192, 3072, 1024);
    attn_k<<<dim3(16, 64), dim3(256), 0, stream>>>(qkv, score);
    gemm_bt<1, 0><<<dim3(8, 64), dim3(256), 0, stream>>>(score, w2bf, b2, (void*)out, 8192, 1024, 1024);
}